// Round 6
// baseline (299.693 us; speedup 1.0000x reference)
//
#include <hip/hip_runtime.h>
#include <hip/hip_bf16.h>
#include <math.h>

#define TT 4096   // tokens (B*S)
#define HH 1024   // hidden
#define EE 8      // experts
#define II 1024   // intermediate

typedef __bf16 bf16x8 __attribute__((ext_vector_type(8)));
typedef float  floatx4 __attribute__((ext_vector_type(4)));
typedef __hip_bfloat16 bf16;

// Rows are 64 elems (128 B) in LDS = 8 chunks of 16 B.
// XOR swizzle: logical chunk lc of row r lives at phys chunk lc ^ (r&7).
// b128 reads then hit all 32 banks at most 2-way (free, m136).
//
// K-loop pipeline (R6): global_load -> VGPR buf (prefetch k+1) -> ds_write (k).
// No global_load_lds: VGPR-dest loads need no vmcnt drain at barriers (no global
// stores in-loop), so the prefetch stays in flight across the barrier — the CK
// pattern. Barriers only drain lgkmcnt (ds_write).

// ---------------- weight transpose+convert: 64x64 tiles, full-line stores ----------------
// tile[p][q] = W[r0+p][c0+q];  d[(c0+row)*1024 + r0+dc+j] = tile[dc+j][row] = W^T. All idx <= 63.
__global__ __launch_bounds__(256) void transpose_convert3(
    const float* __restrict__ Wg, const float* __restrict__ Wu, const float* __restrict__ Wd,
    bf16* __restrict__ wgb, bf16* __restrict__ wub, bf16* __restrict__ wdb) {
  __shared__ float tile[64][65];
  const int zi = blockIdx.z >> 3, e = blockIdx.z & 7;
  const float* s = (zi == 0 ? Wg : zi == 1 ? Wu : Wd) + (size_t)e * 1024 * 1024;
  bf16* d = (zi == 0 ? wgb : zi == 1 ? wub : wdb) + (size_t)e * 1024 * 1024;
  const int tid = threadIdx.x;
  const int r0 = blockIdx.y * 64, c0 = blockIdx.x * 64;
  const int lr = tid >> 4, lc = (tid & 15) * 4;      // load: 16 rows/round x 64 cols
  #pragma unroll
  for (int i = 0; i < 4; i++) {
    float4 v = *(const float4*)(s + (size_t)(r0 + lr + i * 16) * 1024 + c0 + lc);
    tile[lr + i * 16][lc + 0] = v.x;
    tile[lr + i * 16][lc + 1] = v.y;
    tile[lr + i * 16][lc + 2] = v.z;
    tile[lr + i * 16][lc + 3] = v.w;
  }
  __syncthreads();
  const int dr = tid >> 3, dc = (tid & 7) * 8;       // store: 32 rows/round x 64 cols (16B/lane)
  #pragma unroll
  for (int i = 0; i < 2; i++) {
    int row = dr + i * 32;
    bf16 tmp[8];
    #pragma unroll
    for (int j = 0; j < 8; j++) tmp[j] = __float2bfloat16(tile[dc + j][row]);
    *(float4*)(d + (size_t)(c0 + row) * 1024 + r0 + dc) = *(float4*)tmp;
  }
}

// ---------------- router: logits, top-2 -> per-token records; per-block imp partials; x->bf16 ----------------
__global__ __launch_bounds__(256) void router_kernel(
    const float* __restrict__ x, const float* __restrict__ Wr,
    bf16* __restrict__ xb, int* __restrict__ pair, float2* __restrict__ w2,
    float* __restrict__ impPart)
{
  __shared__ float simp[8];
  const int tid = threadIdx.x;
  if (tid < 8) simp[tid] = 0.f;
  __syncthreads();

  const int w = tid >> 6, lane = tid & 63;
  const int t = blockIdx.x * 4 + w;
  const float* xr = x + (size_t)t * HH;
  float acc[8] = {0.f,0.f,0.f,0.f,0.f,0.f,0.f,0.f};
  #pragma unroll
  for (int i = 0; i < 16; i++) {
    int h = lane + i * 64;
    float xv = xr[h];
    xb[(size_t)t * HH + h] = __float2bfloat16(xv);
    const float4* wr = (const float4*)(Wr + h * 8);
    float4 a = wr[0], b = wr[1];
    acc[0] += xv * a.x; acc[1] += xv * a.y; acc[2] += xv * a.z; acc[3] += xv * a.w;
    acc[4] += xv * b.x; acc[5] += xv * b.y; acc[6] += xv * b.z; acc[7] += xv * b.w;
  }
  #pragma unroll
  for (int e = 0; e < 8; e++) {
    #pragma unroll
    for (int off = 32; off > 0; off >>= 1)
      acc[e] += __shfl_xor(acc[e], off);
  }
  if (lane == 0) {
    int i0 = 0;
    #pragma unroll
    for (int e = 1; e < 8; e++) if (acc[e] > acc[i0]) i0 = e;   // lowest index wins ties, like lax.top_k
    int i1 = (i0 == 0) ? 1 : 0;
    #pragma unroll
    for (int e = 0; e < 8; e++) if (e != i0 && acc[e] > acc[i1]) i1 = e;
    float mx = acc[i0];
    float pe[8]; float s = 0.f;
    #pragma unroll
    for (int e = 0; e < 8; e++) { pe[e] = __expf(acc[e] - mx); s += pe[e]; }
    float inv = 1.f / s;
    #pragma unroll
    for (int e = 0; e < 8; e++) atomicAdd(simp + e, pe[e] * inv);   // LDS atomic: cheap
    float p0 = pe[i0] * inv, p1 = pe[i1] * inv;
    float wn2 = 1.f / (p0 + p1);
    pair[t] = i0 | (i1 << 8);
    w2[t] = make_float2(p0 * wn2, p1 * wn2);
  }
  __syncthreads();
  if (tid < 8) impPart[blockIdx.x * 8 + tid] = simp[tid];
}

// ---------------- scatter: per-block LDS histogram -> 8 global atomics/block ----------------
__global__ __launch_bounds__(256) void scatter_kernel(
    const int* __restrict__ pair, const float2* __restrict__ w2,
    int* __restrict__ cnt, int* __restrict__ tok_list, float* __restrict__ gate_ls)
{
  __shared__ int lcnt[8];
  __shared__ int lbase[8];
  const int tid = threadIdx.x;
  const int t = blockIdx.x * 256 + tid;
  if (tid < 8) lcnt[tid] = 0;
  __syncthreads();
  int pr = pair[t];
  float2 ww = w2[t];
  int e0 = pr & 0xff, e1 = pr >> 8;
  int lp0 = atomicAdd(lcnt + e0, 1);
  int lp1 = atomicAdd(lcnt + e1, 1);
  __syncthreads();
  if (tid < 8) lbase[tid] = atomicAdd(cnt + tid, lcnt[tid]);   // 8 global atomics per block
  __syncthreads();
  int p0 = lbase[e0] + lp0, p1 = lbase[e1] + lp1;
  tok_list[e0 * TT + p0] = t; gate_ls[e0 * TT + p0] = ww.x;
  tok_list[e1 * TT + p1] = t; gate_ls[e1 * TT + p1] = ww.y;
}

// ---------------- finalize: reduce imp partials, prefix offsets, aux loss ----------------
__global__ __launch_bounds__(256) void finalize_kernel(
    const int* __restrict__ cnt, const float* __restrict__ impPart,
    int* __restrict__ offs, float* __restrict__ aux_out)
{
  __shared__ float part[256];
  __shared__ float impf[8];
  const int tid = threadIdx.x;
  const int e = tid & 7, r = tid >> 3;          // 32 chunks x 8 experts
  float s = 0.f;
  for (int i = r; i < 1024; i += 32) s += impPart[i * 8 + e];
  part[tid] = s;
  __syncthreads();
  if (tid < 8) {
    float ss = 0.f;
    #pragma unroll
    for (int j = 0; j < 32; j++) ss += part[j * 8 + tid];
    impf[tid] = ss;
  }
  __syncthreads();
  if (tid == 0) {
    int o = 0; float sl = 0.f;
    for (int e2 = 0; e2 < 8; e2++) { offs[e2] = o; o += cnt[e2]; sl += (float)cnt[e2] * impf[e2]; }
    aux_out[0] = (float)EE * 0.01f * sl / ((float)TT * (float)TT);
  }
}

// ---------------- gemm1: inter = silu(A@Wg) * (A@Wu); 128x128 tile, BK=64, 64x64/wave ----------------
__global__ __launch_bounds__(256) void gemm1_kernel(
    const bf16* __restrict__ xb, const bf16* __restrict__ wg, const bf16* __restrict__ wu,
    const int* __restrict__ cnt, const int* __restrict__ offs,
    const int* __restrict__ tok_list, bf16* __restrict__ inter)
{
  const int e = blockIdx.z;
  const int M = cnt[e];
  const int m0 = blockIdx.y * 128;
  if (m0 >= M) return;
  const int n0 = blockIdx.x * 128;
  const int off = offs[e];

  __shared__ alignas(16) bf16 As[128 * 64];   // 16 KB, 16 chunks of 1KB
  __shared__ alignas(16) bf16 Bg[128 * 64];   // 16 KB
  __shared__ alignas(16) bf16 Bu[128 * 64];   // 16 KB
  __shared__ int sTok[128];

  const int tid = threadIdx.x;
  if (tid < 128) {
    int p = m0 + tid;
    sTok[tid] = tok_list[e * TT + (p < M ? p : M - 1)];
  }

  const int w = tid >> 6, lane = tid & 63;
  const int quad = lane >> 4, l16 = lane & 15;
  const int srow = lane >> 3, schunk = lane & 7;   // staging: 8 rows x 8 chunks per issue
  const int wm = (w >> 1) * 64, wn = (w & 1) * 64;

  const bf16* bgp = wg + ((size_t)e * II + n0) * HH;  // [n][k] rows
  const bf16* bup = wu + ((size_t)e * II + n0) * HH;

  floatx4 zero4 = {0.f, 0.f, 0.f, 0.f};
  floatx4 accg[4][4], accu[4][4];
  #pragma unroll
  for (int mi = 0; mi < 4; mi++)
    #pragma unroll
    for (int ni = 0; ni < 4; ni++) { accg[mi][ni] = zero4; accu[mi][ni] = zero4; }

  __syncthreads();  // sTok visible

  // 48 staging chunks (16 A + 16 Bg + 16 Bu), 12 per wave; k-invariant per-lane addrs
  const bf16* src[12]; bf16* ldst[12];
  #pragma unroll
  for (int i = 0; i < 12; i++) {
    int idx = w + 4 * i;
    int q = idx & 15;
    int r = q * 8 + srow;
    int col = ((schunk ^ (r & 7)) << 3);
    if (idx < 16) {
      src[i] = xb + (size_t)sTok[r] * HH + col;
      ldst[i] = As + q * 512 + lane * 8;
    } else if (idx < 32) {
      src[i] = bgp + (size_t)r * HH + col;
      ldst[i] = Bg + q * 512 + lane * 8;
    } else {
      src[i] = bup + (size_t)r * HH + col;
      ldst[i] = Bu + q * 512 + lane * 8;
    }
  }
  // k-invariant swizzled LDS read offsets: [mi/ni][half]
  int offA[4][2], offB[4][2];
  #pragma unroll
  for (int mi = 0; mi < 4; mi++) {
    int r = wm + mi * 16 + l16;
    #pragma unroll
    for (int h = 0; h < 2; h++)
      offA[mi][h] = r * 64 + (((h * 4 + quad) ^ (r & 7)) << 3);
  }
  #pragma unroll
  for (int ni = 0; ni < 4; ni++) {
    int r = wn + ni * 16 + l16;
    #pragma unroll
    for (int h = 0; h < 2; h++)
      offB[ni][h] = r * 64 + (((h * 4 + quad) ^ (r & 7)) << 3);
  }

  // prologue: prefetch k=0 into regs
  floatx4 buf[12];
  #pragma unroll
  for (int i = 0; i < 12; i++) buf[i] = *(const floatx4*)src[i];

  for (int k0 = 0; k0 < HH; k0 += 64) {
    if (k0) __syncthreads();                 // prior compute done reading LDS
    #pragma unroll
    for (int i = 0; i < 12; i++) *(floatx4*)ldst[i] = buf[i];   // ds_write_b128
    if (k0 + 64 < HH) {
      #pragma unroll
      for (int i = 0; i < 12; i++) { src[i] += 64; buf[i] = *(const floatx4*)src[i]; }
    }
    __syncthreads();                         // lgkm drain only; prefetch stays in flight

    bf16x8 af[4][2];
    #pragma unroll
    for (int mi = 0; mi < 4; mi++) {
      af[mi][0] = *(const bf16x8*)(As + offA[mi][0]);
      af[mi][1] = *(const bf16x8*)(As + offA[mi][1]);
    }
    #pragma unroll
    for (int ni = 0; ni < 4; ni++) {
      bf16x8 bg0 = *(const bf16x8*)(Bg + offB[ni][0]);
      bf16x8 bg1 = *(const bf16x8*)(Bg + offB[ni][1]);
      bf16x8 bu0 = *(const bf16x8*)(Bu + offB[ni][0]);
      bf16x8 bu1 = *(const bf16x8*)(Bu + offB[ni][1]);
      #pragma unroll
      for (int mi = 0; mi < 4; mi++) {
        accg[mi][ni] = __builtin_amdgcn_mfma_f32_16x16x32_bf16(af[mi][0], bg0, accg[mi][ni], 0, 0, 0);
        accg[mi][ni] = __builtin_amdgcn_mfma_f32_16x16x32_bf16(af[mi][1], bg1, accg[mi][ni], 0, 0, 0);
        accu[mi][ni] = __builtin_amdgcn_mfma_f32_16x16x32_bf16(af[mi][0], bu0, accu[mi][ni], 0, 0, 0);
        accu[mi][ni] = __builtin_amdgcn_mfma_f32_16x16x32_bf16(af[mi][1], bu1, accu[mi][ni], 0, 0, 0);
      }
    }
  }

  // epilogue: silu(g)*u -> bf16 inter (compact slots), C/D: row=quad*4+reg, col=lane&15
  #pragma unroll
  for (int mi = 0; mi < 4; mi++)
    #pragma unroll
    for (int ni = 0; ni < 4; ni++) {
      #pragma unroll
      for (int r = 0; r < 4; r++) {
        int row = wm + mi * 16 + quad * 4 + r;
        int p = m0 + row;
        if (p < M) {
          float gv = accg[mi][ni][r], uv = accu[mi][ni][r];
          float val = gv / (1.f + __expf(-gv)) * uv;
          inter[(size_t)(off + p) * II + (n0 + wn + ni * 16 + l16)] = __float2bfloat16(val);
        }
      }
    }
}

// ---------------- gemm2: out += gate * (inter @ Wd^T); 128x128 tile, BK=64 ----------------
__global__ __launch_bounds__(256, 2) void gemm2_kernel(
    const bf16* __restrict__ inter, const bf16* __restrict__ wd,
    const int* __restrict__ cnt, const int* __restrict__ offs,
    const int* __restrict__ tok_list, const float* __restrict__ gate_ls,
    float* __restrict__ out)
{
  const int e = blockIdx.z;
  const int M = cnt[e];
  const int m0 = blockIdx.y * 128;
  if (m0 >= M) return;
  const int n0 = blockIdx.x * 128;
  const int off = offs[e];

  __shared__ alignas(16) bf16 As[128 * 64];   // 16 KB
  __shared__ alignas(16) bf16 Bs[128 * 64];   // 16 KB
  __shared__ int sTok[128];
  __shared__ float sGw[128];

  const int tid = threadIdx.x;
  if (tid < 128) {
    int p = m0 + tid;
    int pc = p < M ? p : M - 1;
    sTok[tid] = tok_list[e * TT + pc];
    sGw[tid]  = gate_ls[e * TT + pc];
  }
  const int w = tid >> 6, lane = tid & 63;
  const int quad = lane >> 4, l16 = lane & 15;
  const int srow = lane >> 3, schunk = lane & 7;
  const int wm = (w >> 1) * 64, wn = (w & 1) * 64;
  const bf16* bp = wd + ((size_t)e * HH + n0) * II;   // [n=h][k=i] rows

  floatx4 zero4 = {0.f, 0.f, 0.f, 0.f};
  floatx4 acc[4][4];
  #pragma unroll
  for (int mi = 0; mi < 4; mi++)
    #pragma unroll
    for (int ni = 0; ni < 4; ni++) acc[mi][ni] = zero4;

  __syncthreads();

  // 32 staging chunks (16 A + 16 B), 8 per wave
  const bf16* src[8]; bf16* ldst[8];
  #pragma unroll
  for (int i = 0; i < 8; i++) {
    int idx = w + 4 * i;
    int q = idx & 15;
    int r = q * 8 + srow;
    int col = ((schunk ^ (r & 7)) << 3);
    if (idx < 16) {
      int p = m0 + r; int pc = p < M ? p : M - 1;
      src[i] = inter + (size_t)(off + pc) * II + col;
      ldst[i] = As + q * 512 + lane * 8;
    } else {
      src[i] = bp + (size_t)r * II + col;
      ldst[i] = Bs + q * 512 + lane * 8;
    }
  }
  int offA[4][2], offB[4][2];
  #pragma unroll
  for (int mi = 0; mi < 4; mi++) {
    int r = wm + mi * 16 + l16;
    #pragma unroll
    for (int h = 0; h < 2; h++)
      offA[mi][h] = r * 64 + (((h * 4 + quad) ^ (r & 7)) << 3);
  }
  #pragma unroll
  for (int ni = 0; ni < 4; ni++) {
    int r = wn + ni * 16 + l16;
    #pragma unroll
    for (int h = 0; h < 2; h++)
      offB[ni][h] = r * 64 + (((h * 4 + quad) ^ (r & 7)) << 3);
  }

  floatx4 buf[8];
  #pragma unroll
  for (int i = 0; i < 8; i++) buf[i] = *(const floatx4*)src[i];

  for (int k0 = 0; k0 < II; k0 += 64) {
    if (k0) __syncthreads();
    #pragma unroll
    for (int i = 0; i < 8; i++) *(floatx4*)ldst[i] = buf[i];
    if (k0 + 64 < II) {
      #pragma unroll
      for (int i = 0; i < 8; i++) { src[i] += 64; buf[i] = *(const floatx4*)src[i]; }
    }
    __syncthreads();

    bf16x8 af[4][2];
    #pragma unroll
    for (int mi = 0; mi < 4; mi++) {
      af[mi][0] = *(const bf16x8*)(As + offA[mi][0]);
      af[mi][1] = *(const bf16x8*)(As + offA[mi][1]);
    }
    #pragma unroll
    for (int ni = 0; ni < 4; ni++) {
      bf16x8 b0 = *(const bf16x8*)(Bs + offB[ni][0]);
      bf16x8 b1 = *(const bf16x8*)(Bs + offB[ni][1]);
      #pragma unroll
      for (int mi = 0; mi < 4; mi++) {
        acc[mi][ni] = __builtin_amdgcn_mfma_f32_16x16x32_bf16(af[mi][0], b0, acc[mi][ni], 0, 0, 0);
        acc[mi][ni] = __builtin_amdgcn_mfma_f32_16x16x32_bf16(af[mi][1], b1, acc[mi][ni], 0, 0, 0);
      }
    }
  }

  #pragma unroll
  for (int mi = 0; mi < 4; mi++)
    #pragma unroll
    for (int ni = 0; ni < 4; ni++) {
      #pragma unroll
      for (int r = 0; r < 4; r++) {
        int row = wm + mi * 16 + quad * 4 + r;
        int p = m0 + row;
        if (p < M) {
          float val = acc[mi][ni][r] * sGw[row];
          atomicAdd(out + (size_t)sTok[row] * HH + (n0 + wn + ni * 16 + l16), val);
        }
      }
    }
}

// ---------------- host ----------------
extern "C" void kernel_launch(void* const* d_in, const int* in_sizes, int n_in,
                              void* d_out, int out_size, void* d_ws, size_t ws_size,
                              hipStream_t stream)
{
  const float* x  = (const float*)d_in[0];
  const float* Wr = (const float*)d_in[1];
  const float* Wg = (const float*)d_in[2];
  const float* Wu = (const float*)d_in[3];
  const float* Wd = (const float*)d_in[4];
  float* out = (float*)d_out;
  char* ws = (char*)d_ws;

  // workspace layout (bytes): total ~75.9 MB
  int*    cnt      = (int*)(ws + 0);          // 8 ints (zeroed)
  int*    offs     = (int*)(ws + 256);        // 8 ints
  float*  impPart  = (float*)(ws + 512);      // 1024*8 floats (32 KB)
  int*    pair     = (int*)(ws + 33280);      // T ints (16 KB)
  float2* w2       = (float2*)(ws + 49664);   // T float2 (32 KB)
  int*    tok_list = (int*)(ws + 98304);      // E*T ints   (128 KB)
  float*  gate_ls  = (float*)(ws + 229376);   // E*T floats (128 KB)
  bf16*   xb       = (bf16*)(ws + 360448);    // T*H bf16   (8 MB)
  bf16*   wgb      = (bf16*)(ws + 8749056);   // E*I*H bf16 (16 MB, transposed [e][i][h])
  bf16*   wub      = (bf16*)(ws + 25526272);  // 16 MB
  bf16*   wdb      = (bf16*)(ws + 42303488);  // 16 MB, transposed [e][h][i]
  bf16*   inter    = (bf16*)(ws + 59080704);  // 2T*I bf16  (16 MB, compact slots)

  hipMemsetAsync(ws, 0, 512, stream);                                   // cnt
  hipMemsetAsync(d_out, 0, (size_t)out_size * sizeof(float), stream);   // atomic accum base

  transpose_convert3<<<dim3(16, 16, 24), 256, 0, stream>>>(Wg, Wu, Wd, wgb, wub, wdb);
  router_kernel<<<1024, 256, 0, stream>>>(x, Wr, xb, pair, w2, impPart);
  scatter_kernel<<<16, 256, 0, stream>>>(pair, w2, cnt, tok_list, gate_ls);
  finalize_kernel<<<1, 256, 0, stream>>>(cnt, impPart, offs, out + (size_t)TT * HH);
  gemm1_kernel<<<dim3(8, 32, 8), 256, 0, stream>>>(xb, wgb, wub, cnt, offs, tok_list, inter);
  gemm2_kernel<<<dim3(8, 32, 8), 256, 0, stream>>>(inter, wdb, cnt, offs, tok_list, gate_ls, out);
}

// Round 7
// 271.785 us; speedup vs baseline: 1.1027x; 1.1027x over previous
//
#include <hip/hip_runtime.h>
#include <hip/hip_bf16.h>
#include <math.h>

#define TT 4096   // tokens (B*S)
#define HH 1024   // hidden
#define EE 8      // experts
#define II 1024   // intermediate

typedef __bf16 bf16x8 __attribute__((ext_vector_type(8)));
typedef float  floatx4 __attribute__((ext_vector_type(4)));
typedef __hip_bfloat16 bf16;

// async global->LDS, 16B per lane. LDS dest is wave-uniform base + lane*16;
// global address is per-lane (gather allowed).
__device__ __forceinline__ void async_copy16(const void* g, void* s) {
  __builtin_amdgcn_global_load_lds((__attribute__((address_space(1))) void*)g,
                                   (__attribute__((address_space(3))) void*)s,
                                   16, 0, 0);
}

// Rows are 64 elems (128 B) in LDS = 8 chunks of 16 B.
// XOR swizzle: logical chunk lc of row r lives at phys chunk lc ^ (r&7).
// b128 reads then hit all 32 banks at most 2-way (free, m136).
// R6 post-mortem: register-staged pipeline (VGPR->ds_write) REGRESSED (62->80us);
// global_load_lds staging is the proven structure — kept.

// ---------------- weight transpose+convert: 64x64 tiles, full-line stores ----------------
__global__ __launch_bounds__(256) void transpose_convert3(
    const float* __restrict__ Wg, const float* __restrict__ Wu, const float* __restrict__ Wd,
    bf16* __restrict__ wgb, bf16* __restrict__ wub, bf16* __restrict__ wdb) {
  __shared__ float tile[64][65];
  const int zi = blockIdx.z >> 3, e = blockIdx.z & 7;
  const float* s = (zi == 0 ? Wg : zi == 1 ? Wu : Wd) + (size_t)e * 1024 * 1024;
  bf16* d = (zi == 0 ? wgb : zi == 1 ? wub : wdb) + (size_t)e * 1024 * 1024;
  const int tid = threadIdx.x;
  const int r0 = blockIdx.y * 64, c0 = blockIdx.x * 64;
  const int lr = tid >> 4, lc = (tid & 15) * 4;      // load: 16 rows/round x 64 cols
  #pragma unroll
  for (int i = 0; i < 4; i++) {
    float4 v = *(const float4*)(s + (size_t)(r0 + lr + i * 16) * 1024 + c0 + lc);
    tile[lr + i * 16][lc + 0] = v.x;
    tile[lr + i * 16][lc + 1] = v.y;
    tile[lr + i * 16][lc + 2] = v.z;
    tile[lr + i * 16][lc + 3] = v.w;
  }
  __syncthreads();
  const int dr = tid >> 3, dc = (tid & 7) * 8;       // store: 32 rows/round x 64 cols (16B/lane)
  #pragma unroll
  for (int i = 0; i < 2; i++) {
    int row = dr + i * 32;
    bf16 tmp[8];
    #pragma unroll
    for (int j = 0; j < 8; j++) tmp[j] = __float2bfloat16(tile[dc + j][row]);
    *(float4*)(d + (size_t)(c0 + row) * 1024 + r0 + dc) = *(float4*)tmp;
  }
}

// ---------------- router: logits, top-2 -> per-token records; per-block imp partials; x->bf16 ----------------
__global__ __launch_bounds__(256) void router_kernel(
    const float* __restrict__ x, const float* __restrict__ Wr,
    bf16* __restrict__ xb, int* __restrict__ pair, float2* __restrict__ w2,
    float* __restrict__ impPart)
{
  __shared__ float simp[8];
  const int tid = threadIdx.x;
  if (tid < 8) simp[tid] = 0.f;
  __syncthreads();

  const int w = tid >> 6, lane = tid & 63;
  const int t = blockIdx.x * 4 + w;
  const float* xr = x + (size_t)t * HH;
  float acc[8] = {0.f,0.f,0.f,0.f,0.f,0.f,0.f,0.f};
  #pragma unroll
  for (int i = 0; i < 16; i++) {
    int h = lane + i * 64;
    float xv = xr[h];
    xb[(size_t)t * HH + h] = __float2bfloat16(xv);
    const float4* wr = (const float4*)(Wr + h * 8);
    float4 a = wr[0], b = wr[1];
    acc[0] += xv * a.x; acc[1] += xv * a.y; acc[2] += xv * a.z; acc[3] += xv * a.w;
    acc[4] += xv * b.x; acc[5] += xv * b.y; acc[6] += xv * b.z; acc[7] += xv * b.w;
  }
  #pragma unroll
  for (int e = 0; e < 8; e++) {
    #pragma unroll
    for (int off = 32; off > 0; off >>= 1)
      acc[e] += __shfl_xor(acc[e], off);
  }
  if (lane == 0) {
    int i0 = 0;
    #pragma unroll
    for (int e = 1; e < 8; e++) if (acc[e] > acc[i0]) i0 = e;   // lowest index wins ties, like lax.top_k
    int i1 = (i0 == 0) ? 1 : 0;
    #pragma unroll
    for (int e = 0; e < 8; e++) if (e != i0 && acc[e] > acc[i1]) i1 = e;
    float mx = acc[i0];
    float pe[8]; float s = 0.f;
    #pragma unroll
    for (int e = 0; e < 8; e++) { pe[e] = __expf(acc[e] - mx); s += pe[e]; }
    float inv = 1.f / s;
    #pragma unroll
    for (int e = 0; e < 8; e++) atomicAdd(simp + e, pe[e] * inv);   // LDS atomic: cheap
    float p0 = pe[i0] * inv, p1 = pe[i1] * inv;
    float wn2 = 1.f / (p0 + p1);
    pair[t] = i0 | (i1 << 8);
    w2[t] = make_float2(p0 * wn2, p1 * wn2);
  }
  __syncthreads();
  if (tid < 8) impPart[blockIdx.x * 8 + tid] = simp[tid];
}

// ---------------- scatter: per-block LDS histogram -> 8 global atomics/block ----------------
// Also emits slot2[t] = (e0<<12|p0, e1<<12|p1) for the atomic-free combine.
__global__ __launch_bounds__(256) void scatter_kernel(
    const int* __restrict__ pair, const float2* __restrict__ w2,
    int* __restrict__ cnt, int* __restrict__ tok_list, int2* __restrict__ slot2)
{
  __shared__ int lcnt[8];
  __shared__ int lbase[8];
  const int tid = threadIdx.x;
  const int t = blockIdx.x * 256 + tid;
  if (tid < 8) lcnt[tid] = 0;
  __syncthreads();
  int pr = pair[t];
  int e0 = pr & 0xff, e1 = pr >> 8;
  int lp0 = atomicAdd(lcnt + e0, 1);
  int lp1 = atomicAdd(lcnt + e1, 1);
  __syncthreads();
  if (tid < 8) lbase[tid] = atomicAdd(cnt + tid, lcnt[tid]);   // 8 global atomics per block
  __syncthreads();
  int p0 = lbase[e0] + lp0, p1 = lbase[e1] + lp1;
  tok_list[e0 * TT + p0] = t;
  tok_list[e1 * TT + p1] = t;
  slot2[t] = make_int2((e0 << 12) | p0, (e1 << 12) | p1);
}

// ---------------- finalize: reduce imp partials, prefix offsets, aux loss ----------------
__global__ __launch_bounds__(256) void finalize_kernel(
    const int* __restrict__ cnt, const float* __restrict__ impPart,
    int* __restrict__ offs, float* __restrict__ aux_out)
{
  __shared__ float part[256];
  __shared__ float impf[8];
  const int tid = threadIdx.x;
  const int e = tid & 7, r = tid >> 3;          // 32 chunks x 8 experts
  float s = 0.f;
  for (int i = r; i < 1024; i += 32) s += impPart[i * 8 + e];
  part[tid] = s;
  __syncthreads();
  if (tid < 8) {
    float ss = 0.f;
    #pragma unroll
    for (int j = 0; j < 32; j++) ss += part[j * 8 + tid];
    impf[tid] = ss;
  }
  __syncthreads();
  if (tid == 0) {
    int o = 0; float sl = 0.f;
    for (int e2 = 0; e2 < 8; e2++) { offs[e2] = o; o += cnt[e2]; sl += (float)cnt[e2] * impf[e2]; }
    aux_out[0] = (float)EE * 0.01f * sl / ((float)TT * (float)TT);
  }
}

// ---------------- gemm1: inter = silu(A@Wg) * (A@Wu); 128x128 tile, BK=64, 64x64/wave ----------------
__global__ __launch_bounds__(256, 2) void gemm1_kernel(
    const bf16* __restrict__ xb, const bf16* __restrict__ wg, const bf16* __restrict__ wu,
    const int* __restrict__ cnt, const int* __restrict__ offs,
    const int* __restrict__ tok_list, bf16* __restrict__ inter)
{
  const int e = blockIdx.z;
  const int M = cnt[e];
  const int m0 = blockIdx.y * 128;
  if (m0 >= M) return;
  const int n0 = blockIdx.x * 128;
  const int off = offs[e];

  __shared__ alignas(16) bf16 As[128 * 64];   // 16 KB, 16 chunks of 1KB
  __shared__ alignas(16) bf16 Bg[128 * 64];   // 16 KB
  __shared__ alignas(16) bf16 Bu[128 * 64];   // 16 KB
  __shared__ int sTok[128];

  const int tid = threadIdx.x;
  if (tid < 128) {
    int p = m0 + tid;
    sTok[tid] = tok_list[e * TT + (p < M ? p : M - 1)];
  }

  const int w = tid >> 6, lane = tid & 63;
  const int quad = lane >> 4, l16 = lane & 15;
  const int srow = lane >> 3, schunk = lane & 7;   // staging: 8 rows x 8 chunks per issue
  const int wm = (w >> 1) * 64, wn = (w & 1) * 64;

  const bf16* bgp = wg + ((size_t)e * II + n0) * HH;  // [n][k] rows
  const bf16* bup = wu + ((size_t)e * II + n0) * HH;

  floatx4 zero4 = {0.f, 0.f, 0.f, 0.f};
  floatx4 accg[4][4], accu[4][4];
  #pragma unroll
  for (int mi = 0; mi < 4; mi++)
    #pragma unroll
    for (int ni = 0; ni < 4; ni++) { accg[mi][ni] = zero4; accu[mi][ni] = zero4; }

  __syncthreads();  // sTok visible

  // 48 staging issues (16 A + 16 Bg + 16 Bu), 12 per wave; k-invariant pointers
  const bf16* src[12]; bf16* dst[12];
  #pragma unroll
  for (int i = 0; i < 12; i++) {
    int idx = w + 4 * i;
    int q = idx & 15;
    int r = q * 8 + srow;
    int col = ((schunk ^ (r & 7)) << 3);
    if (idx < 16) {
      src[i] = xb + (size_t)sTok[r] * HH + col;
      dst[i] = As + q * 512;
    } else if (idx < 32) {
      src[i] = bgp + (size_t)r * HH + col;
      dst[i] = Bg + q * 512;
    } else {
      src[i] = bup + (size_t)r * HH + col;
      dst[i] = Bu + q * 512;
    }
  }
  // k-invariant swizzled LDS read offsets: [mi/ni][half]
  int offA[4][2], offB[4][2];
  #pragma unroll
  for (int mi = 0; mi < 4; mi++) {
    int r = wm + mi * 16 + l16;
    #pragma unroll
    for (int h = 0; h < 2; h++)
      offA[mi][h] = r * 64 + (((h * 4 + quad) ^ (r & 7)) << 3);
  }
  #pragma unroll
  for (int ni = 0; ni < 4; ni++) {
    int r = wn + ni * 16 + l16;
    #pragma unroll
    for (int h = 0; h < 2; h++)
      offB[ni][h] = r * 64 + (((h * 4 + quad) ^ (r & 7)) << 3);
  }

  for (int k0 = 0; k0 < HH; k0 += 64) {
    if (k0) __syncthreads();                 // prior compute done before LDS overwrite
    #pragma unroll
    for (int i = 0; i < 12; i++) { async_copy16(src[i], dst[i]); src[i] += 64; }
    __syncthreads();                         // vmcnt drained by barrier semantics

    bf16x8 af[4][2];
    #pragma unroll
    for (int mi = 0; mi < 4; mi++) {
      af[mi][0] = *(const bf16x8*)(As + offA[mi][0]);
      af[mi][1] = *(const bf16x8*)(As + offA[mi][1]);
    }
    #pragma unroll
    for (int ni = 0; ni < 4; ni++) {
      bf16x8 bg0 = *(const bf16x8*)(Bg + offB[ni][0]);
      bf16x8 bg1 = *(const bf16x8*)(Bg + offB[ni][1]);
      bf16x8 bu0 = *(const bf16x8*)(Bu + offB[ni][0]);
      bf16x8 bu1 = *(const bf16x8*)(Bu + offB[ni][1]);
      #pragma unroll
      for (int mi = 0; mi < 4; mi++) {
        accg[mi][ni] = __builtin_amdgcn_mfma_f32_16x16x32_bf16(af[mi][0], bg0, accg[mi][ni], 0, 0, 0);
        accg[mi][ni] = __builtin_amdgcn_mfma_f32_16x16x32_bf16(af[mi][1], bg1, accg[mi][ni], 0, 0, 0);
        accu[mi][ni] = __builtin_amdgcn_mfma_f32_16x16x32_bf16(af[mi][0], bu0, accu[mi][ni], 0, 0, 0);
        accu[mi][ni] = __builtin_amdgcn_mfma_f32_16x16x32_bf16(af[mi][1], bu1, accu[mi][ni], 0, 0, 0);
      }
    }
  }

  // epilogue: silu(g)*u -> bf16 inter (compact slots), C/D: row=quad*4+reg, col=lane&15
  #pragma unroll
  for (int mi = 0; mi < 4; mi++)
    #pragma unroll
    for (int ni = 0; ni < 4; ni++) {
      #pragma unroll
      for (int r = 0; r < 4; r++) {
        int row = wm + mi * 16 + quad * 4 + r;
        int p = m0 + row;
        if (p < M) {
          float gv = accg[mi][ni][r], uv = accu[mi][ni][r];
          float val = gv / (1.f + __expf(-gv)) * uv;
          inter[(size_t)(off + p) * II + (n0 + wn + ni * 16 + l16)] = __float2bfloat16(val);
        }
      }
    }
}

// ---------------- gemm2: Obuf[slot] = inter @ Wd^T (plain stores, no atomics) ----------------
__global__ __launch_bounds__(256, 2) void gemm2_kernel(
    const bf16* __restrict__ inter, const bf16* __restrict__ wd,
    const int* __restrict__ cnt, const int* __restrict__ offs,
    bf16* __restrict__ Obuf)
{
  const int e = blockIdx.z;
  const int M = cnt[e];
  const int m0 = blockIdx.y * 128;
  if (m0 >= M) return;
  const int n0 = blockIdx.x * 128;
  const int off = offs[e];

  __shared__ alignas(16) bf16 As[128 * 64];   // 16 KB
  __shared__ alignas(16) bf16 Bs[128 * 64];   // 16 KB

  const int tid = threadIdx.x;
  const int w = tid >> 6, lane = tid & 63;
  const int quad = lane >> 4, l16 = lane & 15;
  const int srow = lane >> 3, schunk = lane & 7;
  const int wm = (w >> 1) * 64, wn = (w & 1) * 64;
  const bf16* bp = wd + ((size_t)e * HH + n0) * II;   // [n=h][k=i] rows

  floatx4 zero4 = {0.f, 0.f, 0.f, 0.f};
  floatx4 acc[4][4];
  #pragma unroll
  for (int mi = 0; mi < 4; mi++)
    #pragma unroll
    for (int ni = 0; ni < 4; ni++) acc[mi][ni] = zero4;

  // 32 staging issues (16 A + 16 B), 8 per wave
  const bf16* src[8]; bf16* dst[8];
  #pragma unroll
  for (int i = 0; i < 8; i++) {
    int idx = w + 4 * i;
    int q = idx & 15;
    int r = q * 8 + srow;
    int col = ((schunk ^ (r & 7)) << 3);
    if (idx < 16) {
      int p = m0 + r; int pc = p < M ? p : M - 1;
      src[i] = inter + (size_t)(off + pc) * II + col;
      dst[i] = As + q * 512;
    } else {
      src[i] = bp + (size_t)r * II + col;
      dst[i] = Bs + q * 512;
    }
  }
  int offA[4][2], offB[4][2];
  #pragma unroll
  for (int mi = 0; mi < 4; mi++) {
    int r = wm + mi * 16 + l16;
    #pragma unroll
    for (int h = 0; h < 2; h++)
      offA[mi][h] = r * 64 + (((h * 4 + quad) ^ (r & 7)) << 3);
  }
  #pragma unroll
  for (int ni = 0; ni < 4; ni++) {
    int r = wn + ni * 16 + l16;
    #pragma unroll
    for (int h = 0; h < 2; h++)
      offB[ni][h] = r * 64 + (((h * 4 + quad) ^ (r & 7)) << 3);
  }

  for (int k0 = 0; k0 < II; k0 += 64) {
    if (k0) __syncthreads();
    #pragma unroll
    for (int i = 0; i < 8; i++) { async_copy16(src[i], dst[i]); src[i] += 64; }
    __syncthreads();

    bf16x8 af[4][2];
    #pragma unroll
    for (int mi = 0; mi < 4; mi++) {
      af[mi][0] = *(const bf16x8*)(As + offA[mi][0]);
      af[mi][1] = *(const bf16x8*)(As + offA[mi][1]);
    }
    #pragma unroll
    for (int ni = 0; ni < 4; ni++) {
      bf16x8 b0 = *(const bf16x8*)(Bs + offB[ni][0]);
      bf16x8 b1 = *(const bf16x8*)(Bs + offB[ni][1]);
      #pragma unroll
      for (int mi = 0; mi < 4; mi++) {
        acc[mi][ni] = __builtin_amdgcn_mfma_f32_16x16x32_bf16(af[mi][0], b0, acc[mi][ni], 0, 0, 0);
        acc[mi][ni] = __builtin_amdgcn_mfma_f32_16x16x32_bf16(af[mi][1], b1, acc[mi][ni], 0, 0, 0);
      }
    }
  }

  #pragma unroll
  for (int mi = 0; mi < 4; mi++)
    #pragma unroll
    for (int ni = 0; ni < 4; ni++) {
      #pragma unroll
      for (int r = 0; r < 4; r++) {
        int row = wm + mi * 16 + quad * 4 + r;
        int p = m0 + row;
        if (p < M)
          Obuf[(size_t)(off + p) * HH + (n0 + wn + ni * 16 + l16)] = __float2bfloat16(acc[mi][ni][r]);
      }
    }
}

// ---------------- combine: out[t] = g0*Obuf[slot0] + g1*Obuf[slot1] ----------------
__global__ __launch_bounds__(256) void combine_kernel(
    const bf16* __restrict__ Obuf, const int2* __restrict__ slot2,
    const float2* __restrict__ w2, const int* __restrict__ offs,
    float* __restrict__ out)
{
  const int t = blockIdx.x, tid = threadIdx.x;
  int2 s = slot2[t];
  float2 g = w2[t];
  int r0 = offs[s.x >> 12] + (s.x & 4095);
  int r1 = offs[s.y >> 12] + (s.y & 4095);
  const bf16* p0 = Obuf + (size_t)r0 * HH;
  const bf16* p1 = Obuf + (size_t)r1 * HH;
  float* po = out + (size_t)t * HH;
  int h = tid * 4;                         // 4 elems/thread, 8B bf16 reads, 16B fp32 write
  ushort4 a = *(const ushort4*)(p0 + h);
  ushort4 b = *(const ushort4*)(p1 + h);
  float4 o;
  o.x = g.x * __bfloat162float(*(bf16*)&a.x) + g.y * __bfloat162float(*(bf16*)&b.x);
  o.y = g.x * __bfloat162float(*(bf16*)&a.y) + g.y * __bfloat162float(*(bf16*)&b.y);
  o.z = g.x * __bfloat162float(*(bf16*)&a.z) + g.y * __bfloat162float(*(bf16*)&b.z);
  o.w = g.x * __bfloat162float(*(bf16*)&a.w) + g.y * __bfloat162float(*(bf16*)&b.w);
  *(float4*)(po + h) = o;
}

// ---------------- host ----------------
extern "C" void kernel_launch(void* const* d_in, const int* in_sizes, int n_in,
                              void* d_out, int out_size, void* d_ws, size_t ws_size,
                              hipStream_t stream)
{
  const float* x  = (const float*)d_in[0];
  const float* Wr = (const float*)d_in[1];
  const float* Wg = (const float*)d_in[2];
  const float* Wu = (const float*)d_in[3];
  const float* Wd = (const float*)d_in[4];
  float* out = (float*)d_out;
  char* ws = (char*)d_ws;

  // workspace layout (bytes): total ~75.9 MB
  int*    cnt      = (int*)(ws + 0);          // 8 ints (zeroed)
  int*    offs     = (int*)(ws + 256);        // 8 ints
  float*  impPart  = (float*)(ws + 512);      // 1024*8 floats (32 KB)
  int*    pair     = (int*)(ws + 33280);      // T ints (16 KB)
  float2* w2       = (float2*)(ws + 49664);   // T float2 (32 KB)
  int*    tok_list = (int*)(ws + 98304);      // E*T ints   (128 KB)
  int2*   slot2    = (int2*)(ws + 229376);    // T int2     (32 KB)
  bf16*   xb       = (bf16*)(ws + 360448);    // T*H bf16   (8 MB)
  bf16*   wgb      = (bf16*)(ws + 8749056);   // E*I*H bf16 (16 MB, transposed [e][i][h])
  bf16*   wub      = (bf16*)(ws + 25526272);  // 16 MB
  bf16*   wdb      = (bf16*)(ws + 42303488);  // 16 MB, transposed [e][h][i]
  bf16*   inter    = (bf16*)(ws + 59080704);  // 2T*I bf16  (16 MB, compact slots)
  // Obuf aliases wgb: wgb is only read by gemm1, which completes before gemm2
  // writes Obuf (stream-serialized); transpose rewrites wgb next replay, after
  // combine consumed Obuf. Saves 16 MB of workspace.
  bf16*   Obuf     = wgb;

  hipMemsetAsync(ws, 0, 512, stream);                                   // cnt

  transpose_convert3<<<dim3(16, 16, 24), 256, 0, stream>>>(Wg, Wu, Wd, wgb, wub, wdb);
  router_kernel<<<1024, 256, 0, stream>>>(x, Wr, xb, pair, w2, impPart);
  scatter_kernel<<<16, 256, 0, stream>>>(pair, w2, cnt, tok_list, slot2);
  finalize_kernel<<<1, 256, 0, stream>>>(cnt, impPart, offs, out + (size_t)TT * HH);
  gemm1_kernel<<<dim3(8, 32, 8), 256, 0, stream>>>(xb, wgb, wub, cnt, offs, tok_list, inter);
  gemm2_kernel<<<dim3(8, 32, 8), 256, 0, stream>>>(inter, wdb, cnt, offs, Obuf);
  combine_kernel<<<TT, 256, 0, stream>>>(Obuf, slot2, w2, offs, out);
}

// Round 8
// 265.795 us; speedup vs baseline: 1.1275x; 1.0225x over previous
//
#include <hip/hip_runtime.h>
#include <hip/hip_bf16.h>
#include <math.h>

#define TT 4096   // tokens (B*S)
#define HH 1024   // hidden
#define EE 8      // experts
#define II 1024   // intermediate

typedef __bf16 bf16x8 __attribute__((ext_vector_type(8)));
typedef float  floatx4 __attribute__((ext_vector_type(4)));
typedef __hip_bfloat16 bf16;

// async global->LDS, 16B per lane. LDS dest is wave-uniform base + lane*16;
// global address is per-lane (gather allowed).
__device__ __forceinline__ void async_copy16(const void* g, void* s) {
  __builtin_amdgcn_global_load_lds((__attribute__((address_space(1))) void*)g,
                                   (__attribute__((address_space(3))) void*)s,
                                   16, 0, 0);
}

// Rows are 64 elems (128 B) in LDS = 8 chunks of 16 B.
// XOR swizzle: logical chunk lc of row r lives at phys chunk lc ^ (r&7).
// R6 post-mortem: register-staged pipeline REGRESSED; global_load_lds kept.
// R8: 64M x 128N tiles (2x block count vs 128x128) -> 3-4 blocks/CU for
// barrier-drain overlap; per-wave intensity kept via BK=64.

// ---------------- weight transpose+convert: 64x64 tiles, full-line stores ----------------
__global__ __launch_bounds__(256) void transpose_convert3(
    const float* __restrict__ Wg, const float* __restrict__ Wu, const float* __restrict__ Wd,
    bf16* __restrict__ wgb, bf16* __restrict__ wub, bf16* __restrict__ wdb) {
  __shared__ float tile[64][65];
  const int zi = blockIdx.z >> 3, e = blockIdx.z & 7;
  const float* s = (zi == 0 ? Wg : zi == 1 ? Wu : Wd) + (size_t)e * 1024 * 1024;
  bf16* d = (zi == 0 ? wgb : zi == 1 ? wub : wdb) + (size_t)e * 1024 * 1024;
  const int tid = threadIdx.x;
  const int r0 = blockIdx.y * 64, c0 = blockIdx.x * 64;
  const int lr = tid >> 4, lc = (tid & 15) * 4;      // load: 16 rows/round x 64 cols
  #pragma unroll
  for (int i = 0; i < 4; i++) {
    float4 v = *(const float4*)(s + (size_t)(r0 + lr + i * 16) * 1024 + c0 + lc);
    tile[lr + i * 16][lc + 0] = v.x;
    tile[lr + i * 16][lc + 1] = v.y;
    tile[lr + i * 16][lc + 2] = v.z;
    tile[lr + i * 16][lc + 3] = v.w;
  }
  __syncthreads();
  const int dr = tid >> 3, dc = (tid & 7) * 8;       // store: 32 rows/round x 64 cols (16B/lane)
  #pragma unroll
  for (int i = 0; i < 2; i++) {
    int row = dr + i * 32;
    bf16 tmp[8];
    #pragma unroll
    for (int j = 0; j < 8; j++) tmp[j] = __float2bfloat16(tile[dc + j][row]);
    *(float4*)(d + (size_t)(c0 + row) * 1024 + r0 + dc) = *(float4*)tmp;
  }
}

// ---------------- router: logits, top-2 -> per-token records; per-block imp partials; x->bf16 ----------------
__global__ __launch_bounds__(256) void router_kernel(
    const float* __restrict__ x, const float* __restrict__ Wr,
    bf16* __restrict__ xb, int* __restrict__ pair, float2* __restrict__ w2,
    float* __restrict__ impPart)
{
  __shared__ float simp[8];
  const int tid = threadIdx.x;
  if (tid < 8) simp[tid] = 0.f;
  __syncthreads();

  const int w = tid >> 6, lane = tid & 63;
  const int t = blockIdx.x * 4 + w;
  const float* xr = x + (size_t)t * HH;
  float acc[8] = {0.f,0.f,0.f,0.f,0.f,0.f,0.f,0.f};
  #pragma unroll
  for (int i = 0; i < 16; i++) {
    int h = lane + i * 64;
    float xv = xr[h];
    xb[(size_t)t * HH + h] = __float2bfloat16(xv);
    const float4* wr = (const float4*)(Wr + h * 8);
    float4 a = wr[0], b = wr[1];
    acc[0] += xv * a.x; acc[1] += xv * a.y; acc[2] += xv * a.z; acc[3] += xv * a.w;
    acc[4] += xv * b.x; acc[5] += xv * b.y; acc[6] += xv * b.z; acc[7] += xv * b.w;
  }
  #pragma unroll
  for (int e = 0; e < 8; e++) {
    #pragma unroll
    for (int off = 32; off > 0; off >>= 1)
      acc[e] += __shfl_xor(acc[e], off);
  }
  if (lane == 0) {
    int i0 = 0;
    #pragma unroll
    for (int e = 1; e < 8; e++) if (acc[e] > acc[i0]) i0 = e;   // lowest index wins ties, like lax.top_k
    int i1 = (i0 == 0) ? 1 : 0;
    #pragma unroll
    for (int e = 0; e < 8; e++) if (e != i0 && acc[e] > acc[i1]) i1 = e;
    float mx = acc[i0];
    float pe[8]; float s = 0.f;
    #pragma unroll
    for (int e = 0; e < 8; e++) { pe[e] = __expf(acc[e] - mx); s += pe[e]; }
    float inv = 1.f / s;
    #pragma unroll
    for (int e = 0; e < 8; e++) atomicAdd(simp + e, pe[e] * inv);   // LDS atomic: cheap
    float p0 = pe[i0] * inv, p1 = pe[i1] * inv;
    float wn2 = 1.f / (p0 + p1);
    pair[t] = i0 | (i1 << 8);
    w2[t] = make_float2(p0 * wn2, p1 * wn2);
  }
  __syncthreads();
  if (tid < 8) impPart[blockIdx.x * 8 + tid] = simp[tid];
}

// ---------------- scatter: per-block LDS histogram -> 8 global atomics/block ----------------
__global__ __launch_bounds__(256) void scatter_kernel(
    const int* __restrict__ pair, const float2* __restrict__ w2,
    int* __restrict__ cnt, int* __restrict__ tok_list, int2* __restrict__ slot2)
{
  __shared__ int lcnt[8];
  __shared__ int lbase[8];
  const int tid = threadIdx.x;
  const int t = blockIdx.x * 256 + tid;
  if (tid < 8) lcnt[tid] = 0;
  __syncthreads();
  int pr = pair[t];
  int e0 = pr & 0xff, e1 = pr >> 8;
  int lp0 = atomicAdd(lcnt + e0, 1);
  int lp1 = atomicAdd(lcnt + e1, 1);
  __syncthreads();
  if (tid < 8) lbase[tid] = atomicAdd(cnt + tid, lcnt[tid]);   // 8 global atomics per block
  __syncthreads();
  int p0 = lbase[e0] + lp0, p1 = lbase[e1] + lp1;
  tok_list[e0 * TT + p0] = t;
  tok_list[e1 * TT + p1] = t;
  slot2[t] = make_int2((e0 << 12) | p0, (e1 << 12) | p1);
}

// ---------------- finalize: reduce imp partials, prefix offsets, aux loss ----------------
__global__ __launch_bounds__(256) void finalize_kernel(
    const int* __restrict__ cnt, const float* __restrict__ impPart,
    int* __restrict__ offs, float* __restrict__ aux_out)
{
  __shared__ float part[256];
  __shared__ float impf[8];
  const int tid = threadIdx.x;
  const int e = tid & 7, r = tid >> 3;          // 32 chunks x 8 experts
  float s = 0.f;
  for (int i = r; i < 1024; i += 32) s += impPart[i * 8 + e];
  part[tid] = s;
  __syncthreads();
  if (tid < 8) {
    float ss = 0.f;
    #pragma unroll
    for (int j = 0; j < 32; j++) ss += part[j * 8 + tid];
    impf[tid] = ss;
  }
  __syncthreads();
  if (tid == 0) {
    int o = 0; float sl = 0.f;
    for (int e2 = 0; e2 < 8; e2++) { offs[e2] = o; o += cnt[e2]; sl += (float)cnt[e2] * impf[e2]; }
    aux_out[0] = (float)EE * 0.01f * sl / ((float)TT * (float)TT);
  }
}

// ---------------- gemm1: inter = silu(A@Wg) * (A@Wu); 64x128 tile, BK=64, 32x64/wave ----------------
__global__ __launch_bounds__(256, 3) void gemm1_kernel(
    const bf16* __restrict__ xb, const bf16* __restrict__ wg, const bf16* __restrict__ wu,
    const int* __restrict__ cnt, const int* __restrict__ offs,
    const int* __restrict__ tok_list, bf16* __restrict__ inter)
{
  const int e = blockIdx.z;
  const int M = cnt[e];
  const int m0 = blockIdx.y * 64;
  if (m0 >= M) return;
  const int n0 = blockIdx.x * 128;
  const int off = offs[e];

  __shared__ alignas(16) bf16 As[64 * 64];    // 8 KB, 8 chunks of 1KB
  __shared__ alignas(16) bf16 Bg[128 * 64];   // 16 KB, 16 chunks
  __shared__ alignas(16) bf16 Bu[128 * 64];   // 16 KB
  __shared__ int sTok[64];

  const int tid = threadIdx.x;
  if (tid < 64) {
    int p = m0 + tid;
    sTok[tid] = tok_list[e * TT + (p < M ? p : M - 1)];
  }

  const int w = tid >> 6, lane = tid & 63;
  const int quad = lane >> 4, l16 = lane & 15;
  const int srow = lane >> 3, schunk = lane & 7;   // staging: 8 rows x 8 chunks per issue
  const int wm = (w & 1) * 32, wn = (w >> 1) * 64;

  const bf16* bgp = wg + ((size_t)e * II + n0) * HH;  // [n][k] rows
  const bf16* bup = wu + ((size_t)e * II + n0) * HH;

  floatx4 zero4 = {0.f, 0.f, 0.f, 0.f};
  floatx4 accg[2][4], accu[2][4];
  #pragma unroll
  for (int mi = 0; mi < 2; mi++)
    #pragma unroll
    for (int ni = 0; ni < 4; ni++) { accg[mi][ni] = zero4; accu[mi][ni] = zero4; }

  __syncthreads();  // sTok visible

  // 40 staging issues (8 A + 16 Bg + 16 Bu), 10 per wave; k-invariant pointers
  const bf16* src[10]; bf16* dst[10];
  #pragma unroll
  for (int i = 0; i < 10; i++) {
    int idx = w + 4 * i;
    if (idx < 8) {
      int q = idx, r = q * 8 + srow;
      int col = ((schunk ^ (r & 7)) << 3);
      src[i] = xb + (size_t)sTok[r] * HH + col;
      dst[i] = As + q * 512;
    } else if (idx < 24) {
      int q = idx - 8, r = q * 8 + srow;
      int col = ((schunk ^ (r & 7)) << 3);
      src[i] = bgp + (size_t)r * HH + col;
      dst[i] = Bg + q * 512;
    } else {
      int q = idx - 24, r = q * 8 + srow;
      int col = ((schunk ^ (r & 7)) << 3);
      src[i] = bup + (size_t)r * HH + col;
      dst[i] = Bu + q * 512;
    }
  }
  // k-invariant swizzled LDS read offsets: [mi/ni][half]
  int offA[2][2], offB[4][2];
  #pragma unroll
  for (int mi = 0; mi < 2; mi++) {
    int r = wm + mi * 16 + l16;
    #pragma unroll
    for (int h = 0; h < 2; h++)
      offA[mi][h] = r * 64 + (((h * 4 + quad) ^ (r & 7)) << 3);
  }
  #pragma unroll
  for (int ni = 0; ni < 4; ni++) {
    int r = wn + ni * 16 + l16;
    #pragma unroll
    for (int h = 0; h < 2; h++)
      offB[ni][h] = r * 64 + (((h * 4 + quad) ^ (r & 7)) << 3);
  }

  for (int k0 = 0; k0 < HH; k0 += 64) {
    if (k0) __syncthreads();                 // prior compute done before LDS overwrite
    #pragma unroll
    for (int i = 0; i < 10; i++) { async_copy16(src[i], dst[i]); src[i] += 64; }
    __syncthreads();                         // vmcnt drained by barrier semantics

    bf16x8 af[2][2];
    #pragma unroll
    for (int mi = 0; mi < 2; mi++) {
      af[mi][0] = *(const bf16x8*)(As + offA[mi][0]);
      af[mi][1] = *(const bf16x8*)(As + offA[mi][1]);
    }
    #pragma unroll
    for (int ni = 0; ni < 4; ni++) {
      bf16x8 bg0 = *(const bf16x8*)(Bg + offB[ni][0]);
      bf16x8 bg1 = *(const bf16x8*)(Bg + offB[ni][1]);
      bf16x8 bu0 = *(const bf16x8*)(Bu + offB[ni][0]);
      bf16x8 bu1 = *(const bf16x8*)(Bu + offB[ni][1]);
      #pragma unroll
      for (int mi = 0; mi < 2; mi++) {
        accg[mi][ni] = __builtin_amdgcn_mfma_f32_16x16x32_bf16(af[mi][0], bg0, accg[mi][ni], 0, 0, 0);
        accg[mi][ni] = __builtin_amdgcn_mfma_f32_16x16x32_bf16(af[mi][1], bg1, accg[mi][ni], 0, 0, 0);
        accu[mi][ni] = __builtin_amdgcn_mfma_f32_16x16x32_bf16(af[mi][0], bu0, accu[mi][ni], 0, 0, 0);
        accu[mi][ni] = __builtin_amdgcn_mfma_f32_16x16x32_bf16(af[mi][1], bu1, accu[mi][ni], 0, 0, 0);
      }
    }
  }

  // epilogue: silu(g)*u -> bf16 inter (compact slots), C/D: row=quad*4+reg, col=lane&15
  #pragma unroll
  for (int mi = 0; mi < 2; mi++)
    #pragma unroll
    for (int ni = 0; ni < 4; ni++) {
      #pragma unroll
      for (int r = 0; r < 4; r++) {
        int row = wm + mi * 16 + quad * 4 + r;
        int p = m0 + row;
        if (p < M) {
          float gv = accg[mi][ni][r], uv = accu[mi][ni][r];
          float val = gv / (1.f + __expf(-gv)) * uv;
          inter[(size_t)(off + p) * II + (n0 + wn + ni * 16 + l16)] = __float2bfloat16(val);
        }
      }
    }
}

// ---------------- gemm2: Obuf[slot] = inter @ Wd^T; 64x128 tile, BK=64 ----------------
__global__ __launch_bounds__(256, 4) void gemm2_kernel(
    const bf16* __restrict__ inter, const bf16* __restrict__ wd,
    const int* __restrict__ cnt, const int* __restrict__ offs,
    bf16* __restrict__ Obuf)
{
  const int e = blockIdx.z;
  const int M = cnt[e];
  const int m0 = blockIdx.y * 64;
  if (m0 >= M) return;
  const int n0 = blockIdx.x * 128;
  const int off = offs[e];

  __shared__ alignas(16) bf16 As[64 * 64];    // 8 KB
  __shared__ alignas(16) bf16 Bs[128 * 64];   // 16 KB

  const int tid = threadIdx.x;
  const int w = tid >> 6, lane = tid & 63;
  const int quad = lane >> 4, l16 = lane & 15;
  const int srow = lane >> 3, schunk = lane & 7;
  const int wm = (w & 1) * 32, wn = (w >> 1) * 64;
  const bf16* bp = wd + ((size_t)e * HH + n0) * II;   // [n=h][k=i] rows

  floatx4 zero4 = {0.f, 0.f, 0.f, 0.f};
  floatx4 acc[2][4];
  #pragma unroll
  for (int mi = 0; mi < 2; mi++)
    #pragma unroll
    for (int ni = 0; ni < 4; ni++) acc[mi][ni] = zero4;

  // 24 staging issues (8 A + 16 B), 6 per wave
  const bf16* src[6]; bf16* dst[6];
  #pragma unroll
  for (int i = 0; i < 6; i++) {
    int idx = w + 4 * i;
    if (idx < 8) {
      int q = idx, r = q * 8 + srow;
      int col = ((schunk ^ (r & 7)) << 3);
      int p = m0 + r; int pc = p < M ? p : M - 1;
      src[i] = inter + (size_t)(off + pc) * II + col;
      dst[i] = As + q * 512;
    } else {
      int q = idx - 8, r = q * 8 + srow;
      int col = ((schunk ^ (r & 7)) << 3);
      src[i] = bp + (size_t)r * II + col;
      dst[i] = Bs + q * 512;
    }
  }
  int offA[2][2], offB[4][2];
  #pragma unroll
  for (int mi = 0; mi < 2; mi++) {
    int r = wm + mi * 16 + l16;
    #pragma unroll
    for (int h = 0; h < 2; h++)
      offA[mi][h] = r * 64 + (((h * 4 + quad) ^ (r & 7)) << 3);
  }
  #pragma unroll
  for (int ni = 0; ni < 4; ni++) {
    int r = wn + ni * 16 + l16;
    #pragma unroll
    for (int h = 0; h < 2; h++)
      offB[ni][h] = r * 64 + (((h * 4 + quad) ^ (r & 7)) << 3);
  }

  for (int k0 = 0; k0 < II; k0 += 64) {
    if (k0) __syncthreads();
    #pragma unroll
    for (int i = 0; i < 6; i++) { async_copy16(src[i], dst[i]); src[i] += 64; }
    __syncthreads();

    bf16x8 af[2][2];
    #pragma unroll
    for (int mi = 0; mi < 2; mi++) {
      af[mi][0] = *(const bf16x8*)(As + offA[mi][0]);
      af[mi][1] = *(const bf16x8*)(As + offA[mi][1]);
    }
    #pragma unroll
    for (int ni = 0; ni < 4; ni++) {
      bf16x8 b0 = *(const bf16x8*)(Bs + offB[ni][0]);
      bf16x8 b1 = *(const bf16x8*)(Bs + offB[ni][1]);
      #pragma unroll
      for (int mi = 0; mi < 2; mi++) {
        acc[mi][ni] = __builtin_amdgcn_mfma_f32_16x16x32_bf16(af[mi][0], b0, acc[mi][ni], 0, 0, 0);
        acc[mi][ni] = __builtin_amdgcn_mfma_f32_16x16x32_bf16(af[mi][1], b1, acc[mi][ni], 0, 0, 0);
      }
    }
  }

  #pragma unroll
  for (int mi = 0; mi < 2; mi++)
    #pragma unroll
    for (int ni = 0; ni < 4; ni++) {
      #pragma unroll
      for (int r = 0; r < 4; r++) {
        int row = wm + mi * 16 + quad * 4 + r;
        int p = m0 + row;
        if (p < M)
          Obuf[(size_t)(off + p) * HH + (n0 + wn + ni * 16 + l16)] = __float2bfloat16(acc[mi][ni][r]);
      }
    }
}

// ---------------- combine: out[t] = g0*Obuf[slot0] + g1*Obuf[slot1] ----------------
__global__ __launch_bounds__(256) void combine_kernel(
    const bf16* __restrict__ Obuf, const int2* __restrict__ slot2,
    const float2* __restrict__ w2, const int* __restrict__ offs,
    float* __restrict__ out)
{
  const int t = blockIdx.x, tid = threadIdx.x;
  int2 s = slot2[t];
  float2 g = w2[t];
  int r0 = offs[s.x >> 12] + (s.x & 4095);
  int r1 = offs[s.y >> 12] + (s.y & 4095);
  const bf16* p0 = Obuf + (size_t)r0 * HH;
  const bf16* p1 = Obuf + (size_t)r1 * HH;
  float* po = out + (size_t)t * HH;
  int h = tid * 4;                         // 4 elems/thread, 8B bf16 reads, 16B fp32 write
  ushort4 a = *(const ushort4*)(p0 + h);
  ushort4 b = *(const ushort4*)(p1 + h);
  float4 o;
  o.x = g.x * __bfloat162float(*(bf16*)&a.x) + g.y * __bfloat162float(*(bf16*)&b.x);
  o.y = g.x * __bfloat162float(*(bf16*)&a.y) + g.y * __bfloat162float(*(bf16*)&b.y);
  o.z = g.x * __bfloat162float(*(bf16*)&a.z) + g.y * __bfloat162float(*(bf16*)&b.z);
  o.w = g.x * __bfloat162float(*(bf16*)&a.w) + g.y * __bfloat162float(*(bf16*)&b.w);
  *(float4*)(po + h) = o;
}

// ---------------- host ----------------
extern "C" void kernel_launch(void* const* d_in, const int* in_sizes, int n_in,
                              void* d_out, int out_size, void* d_ws, size_t ws_size,
                              hipStream_t stream)
{
  const float* x  = (const float*)d_in[0];
  const float* Wr = (const float*)d_in[1];
  const float* Wg = (const float*)d_in[2];
  const float* Wu = (const float*)d_in[3];
  const float* Wd = (const float*)d_in[4];
  float* out = (float*)d_out;
  char* ws = (char*)d_ws;

  // workspace layout (bytes): total ~75.9 MB
  int*    cnt      = (int*)(ws + 0);          // 8 ints (zeroed)
  int*    offs     = (int*)(ws + 256);        // 8 ints
  float*  impPart  = (float*)(ws + 512);      // 1024*8 floats (32 KB)
  int*    pair     = (int*)(ws + 33280);      // T ints (16 KB)
  float2* w2       = (float2*)(ws + 49664);   // T float2 (32 KB)
  int*    tok_list = (int*)(ws + 98304);      // E*T ints   (128 KB)
  int2*   slot2    = (int2*)(ws + 229376);    // T int2     (32 KB)
  bf16*   xb       = (bf16*)(ws + 360448);    // T*H bf16   (8 MB)
  bf16*   wgb      = (bf16*)(ws + 8749056);   // E*I*H bf16 (16 MB, transposed [e][i][h])
  bf16*   wub      = (bf16*)(ws + 25526272);  // 16 MB
  bf16*   wdb      = (bf16*)(ws + 42303488);  // 16 MB, transposed [e][h][i]
  bf16*   inter    = (bf16*)(ws + 59080704);  // 2T*I bf16  (16 MB, compact slots)
  // Obuf aliases wgb: wgb is only read by gemm1, which completes before gemm2
  // writes Obuf (stream-serialized); transpose rewrites wgb next replay.
  bf16*   Obuf     = wgb;

  hipMemsetAsync(ws, 0, 512, stream);                                   // cnt

  transpose_convert3<<<dim3(16, 16, 24), 256, 0, stream>>>(Wg, Wu, Wd, wgb, wub, wdb);
  router_kernel<<<1024, 256, 0, stream>>>(x, Wr, xb, pair, w2, impPart);
  scatter_kernel<<<16, 256, 0, stream>>>(pair, w2, cnt, tok_list, slot2);
  finalize_kernel<<<1, 256, 0, stream>>>(cnt, impPart, offs, out + (size_t)TT * HH);
  gemm1_kernel<<<dim3(8, 64, 8), 256, 0, stream>>>(xb, wgb, wub, cnt, offs, tok_list, inter);
  gemm2_kernel<<<dim3(8, 64, 8), 256, 0, stream>>>(inter, wdb, cnt, offs, Obuf);
  combine_kernel<<<TT, 256, 0, stream>>>(Obuf, slot2, w2, offs, out);
}